// Round 5
// baseline (25.791 us; speedup 1.0000x reference)
//
#include <hip/hip_runtime.h>

// out[i] = MLP(emb_user[uid[i]]) + MLP(emb_movie[mid[i]])
// bf16 MFMA 16x16x32, fp32 acc.
//
// prep_weights (once, 6 blocks): W1 -> sigma-permuted bf16 A-frags w1g (32KB),
// W2 -> bf16 A-frags w2g (64KB), both in d_ws, frag = 1KB at base+lane*16.
//
// main: per block (256 thr = 4 waves, 32 samples/wave):
//   - issue 16 embedding-gather float4s (HBM long pole) first
//   - DMA-stage w2g into LDS via global_load_lds (16B/lane, linear layout,
//     16 issues/wave, no VGPR round-trip)
//   - W1 frags read straight from global in the main loop (L1-resident 32KB)
//   - sigma trick (round 4): layer-1 accumulators ARE the layer-2 B-frag ->
//     cvt_pk to bf16, no h1 LDS, no shuffles
// LDS 64KB -> 2 blocks/CU, 512 blocks all co-resident; one block's MFMA
// phase hides the other's gather/stage phase.

typedef __attribute__((ext_vector_type(8))) short bf16x8;
typedef __attribute__((ext_vector_type(4))) float f32x4;

__device__ __forceinline__ unsigned int cvt_pk(float lo, float hi) {
  unsigned int r;
  asm("v_cvt_pk_bf16_f32 %0, %1, %2" : "=v"(r) : "v"(lo), "v"(hi));
  return r;  // bf16(lo) in [15:0], bf16(hi) in [31:16], RNE
}

// ---- prep: weights -> bf16 fragment order in d_ws (mapping == round 4) ----
__global__ __launch_bounds__(512) void prep_weights(
    const float* __restrict__ W1, const float* __restrict__ W2,
    unsigned short* __restrict__ w1g, unsigned short* __restrict__ w2g) {
  const int tid = threadIdx.x;
  const int b = blockIdx.x;  // 0..5
  if (b < 2) {
    // W1 [64][256] -> sigma-permuted frags: position p=16nt+4g+r carries
    // channel c=8g+4nt+r (within each 32-chunk hq).
    const int u = tid & 63;
    const int qd = (tid >> 6) + 8 * b;  // k-quad 0..15
    const float* src = W1 + (qd * 4) * 256 + 4 * u;
    const float4 r0 = *(const float4*)(src);
    const float4 r1 = *(const float4*)(src + 256);
    const float4 r2 = *(const float4*)(src + 512);
    const float4 r3 = *(const float4*)(src + 768);
    const float c0[4] = {r0.x, r0.y, r0.z, r0.w};
    const float c1[4] = {r1.x, r1.y, r1.z, r1.w};
    const float c2[4] = {r2.x, r2.y, r2.z, r2.w};
    const float c3[4] = {r3.x, r3.y, r3.z, r3.w};
    const int kt = qd >> 3, gg = (qd >> 1) & 3, bo = (qd & 1) * 4;
#pragma unroll
    for (int p = 0; p < 4; ++p) {
      const int n = 4 * u + p;  // logical channel
      const int hq = n >> 5, cl = n & 31;
      const int nt = (cl >> 2) & 1, mm = 4 * (cl >> 3) + (cl & 3);
      const int fi = hq * 4 + nt * 2 + kt;
      uint2 pk;
      pk.x = cvt_pk(c0[p], c1[p]);
      pk.y = cvt_pk(c2[p], c3[p]);
      *(uint2*)&w1g[fi * 512 + (gg * 16 + mm) * 8 + bo] = pk;
    }
  } else {
    // W2 [256][128] -> plain A-frag order, frag index nt2*8+hq.
    const int u2 = tid & 31;
    const int qd = (tid >> 5) + 16 * (b - 2);  // k-quad 0..63
    const float* src = W2 + (qd * 4) * 128 + 4 * u2;
    const float4 r0 = *(const float4*)(src);
    const float4 r1 = *(const float4*)(src + 128);
    const float4 r2 = *(const float4*)(src + 256);
    const float4 r3 = *(const float4*)(src + 384);
    const float c0[4] = {r0.x, r0.y, r0.z, r0.w};
    const float c1[4] = {r1.x, r1.y, r1.z, r1.w};
    const float c2[4] = {r2.x, r2.y, r2.z, r2.w};
    const float c3[4] = {r3.x, r3.y, r3.z, r3.w};
    const int hq2 = qd >> 3, gg = (qd >> 1) & 3, bo = (qd & 1) * 4;
#pragma unroll
    for (int p = 0; p < 4; ++p) {
      const int n = 4 * u2 + p, nt2 = n >> 4, mm = n & 15;
      uint2 pk;
      pk.x = cvt_pk(c0[p], c1[p]);
      pk.y = cvt_pk(c2[p], c3[p]);
      *(uint2*)&w2g[(nt2 * 8 + hq2) * 512 + (gg * 16 + mm) * 8 + bo] = pk;
    }
  }
}

__global__ __launch_bounds__(256, 2) void movielens_mlp(
    const int* __restrict__ uids, const int* __restrict__ mids,
    const float* __restrict__ EU, const float* __restrict__ EM,
    const unsigned short* __restrict__ w1g, const float* __restrict__ B1,
    const unsigned short* __restrict__ w2g, const float* __restrict__ B2,
    const float* __restrict__ W3, const float* __restrict__ B3,
    float* __restrict__ out) {
  __shared__ __align__(16) unsigned short w2f[64 * 512];  // 64 KB

  const int tid = threadIdx.x;
  const int lane = tid & 63, wv = tid >> 6;  // 4 waves
  const int m = lane & 15, g = lane >> 4;

  const int sbase = blockIdx.x * 128 + wv * 32;
  const int su = sbase + m, sv = su + 16;

  // ---- issue embedding gathers first (HBM, caches flushed per replay) ----
  const float* rp[4];
  rp[0] = EU + (size_t)uids[su] * 64;
  rp[1] = EU + (size_t)uids[sv] * 64;
  rp[2] = EM + (size_t)mids[su] * 64;
  rp[3] = EM + (size_t)mids[sv] * 64;
  float4 xr[4][2][2];
#pragma unroll
  for (int mt = 0; mt < 4; ++mt)
#pragma unroll
    for (int kt = 0; kt < 2; ++kt) {
      xr[mt][kt][0] = *(const float4*)(rp[mt] + kt * 32 + 8 * g);
      xr[mt][kt][1] = *(const float4*)(rp[mt] + kt * 32 + 8 * g + 4);
    }

  // ---- DMA-stage W2 frags into LDS (linear: dest = base + lane*16) ----
#pragma unroll
  for (int f = 0; f < 16; ++f) {
    const int fi = wv * 16 + f;
    __builtin_amdgcn_global_load_lds(
        (const __attribute__((address_space(1))) unsigned int*)(const void*)(
            w2g + fi * 512 + lane * 8),
        (__attribute__((address_space(3))) unsigned int*)(void*)(&w2f[fi * 512]),
        16, 0, 0);
  }

  // ---- convert gathers to layer-1 B-frags (waits gathers, not DMA) ----
  bf16x8 xf[4][2];
#pragma unroll
  for (int mt = 0; mt < 4; ++mt)
#pragma unroll
    for (int kt = 0; kt < 2; ++kt) {
      const float4 a = xr[mt][kt][0], b = xr[mt][kt][1];
      uint4 t;
      t.x = cvt_pk(a.x, a.y);
      t.y = cvt_pk(a.z, a.w);
      t.z = cvt_pk(b.x, b.y);
      t.w = cvt_pk(b.z, b.w);
      xf[mt][kt] = __builtin_bit_cast(bf16x8, t);
    }
  __syncthreads();  // drains DMA (vmcnt 0) + joins waves

  // ---- layer-2 accumulators, bias-initialized ----
  f32x4 acc2[4][8];
#pragma unroll
  for (int nt2 = 0; nt2 < 8; ++nt2) {
    const float4 bv = *(const float4*)(B2 + nt2 * 16 + 4 * g);
#pragma unroll
    for (int mt = 0; mt < 4; ++mt) {
      acc2[mt][nt2][0] = bv.x; acc2[mt][nt2][1] = bv.y;
      acc2[mt][nt2][2] = bv.z; acc2[mt][nt2][3] = bv.w;
    }
  }

  // ---- main loop: layer-1 channels in 8 chunks of 32, register handoff ----
#pragma unroll 2
  for (int hq = 0; hq < 8; ++hq) {
    uint4 hw[4];
#pragma unroll
    for (int nt = 0; nt < 2; ++nt) {
      const unsigned short* wp = w1g + (hq * 4 + nt * 2) * 512 + lane * 8;
      const bf16x8 wa0 = *(const bf16x8*)(wp);         // L1-resident
      const bf16x8 wa1 = *(const bf16x8*)(wp + 512);
      const float4 b1v = *(const float4*)(B1 + hq * 32 + 8 * g + 4 * nt);
#pragma unroll
      for (int mt = 0; mt < 4; ++mt) {
        f32x4 acc;
        acc[0] = b1v.x; acc[1] = b1v.y; acc[2] = b1v.z; acc[3] = b1v.w;
        acc = __builtin_amdgcn_mfma_f32_16x16x32_bf16(wa0, xf[mt][0], acc, 0, 0, 0);
        acc = __builtin_amdgcn_mfma_f32_16x16x32_bf16(wa1, xf[mt][1], acc, 0, 0, 0);
        const unsigned int wlo = cvt_pk(fmaxf(acc[0], 0.f), fmaxf(acc[1], 0.f));
        const unsigned int whi = cvt_pk(fmaxf(acc[2], 0.f), fmaxf(acc[3], 0.f));
        if (nt == 0) { hw[mt].x = wlo; hw[mt].y = whi; }
        else         { hw[mt].z = wlo; hw[mt].w = whi; }
      }
    }
#pragma unroll
    for (int nt2 = 0; nt2 < 8; ++nt2) {
      const bf16x8 w2v = *(const bf16x8*)&w2f[(nt2 * 8 + hq) * 512 + lane * 8];
#pragma unroll
      for (int mt = 0; mt < 4; ++mt)
        acc2[mt][nt2] = __builtin_amdgcn_mfma_f32_16x16x32_bf16(
            w2v, __builtin_bit_cast(bf16x8, hw[mt]), acc2[mt][nt2], 0, 0, 0);
    }
  }

  // ---- layer 3: relu(h2) . W3, reduce across g-groups ----
  const float b3v = B3[0];
  float part[4] = {0.f, 0.f, 0.f, 0.f};
#pragma unroll
  for (int nt2 = 0; nt2 < 8; ++nt2) {
    const float4 w3v = *(const float4*)(W3 + nt2 * 16 + 4 * g);
#pragma unroll
    for (int mt = 0; mt < 4; ++mt) {
      const f32x4 c = acc2[mt][nt2];
      part[mt] += fmaxf(c[0], 0.f) * w3v.x + fmaxf(c[1], 0.f) * w3v.y +
                  fmaxf(c[2], 0.f) * w3v.z + fmaxf(c[3], 0.f) * w3v.w;
    }
  }
#pragma unroll
  for (int mt = 0; mt < 4; ++mt) {
    part[mt] += __shfl_xor(part[mt], 16, 64);
    part[mt] += __shfl_xor(part[mt], 32, 64);
  }
  if (lane < 16) {
    out[sbase + lane] = part[0] + part[2] + 2.f * b3v;
  } else if (lane < 32) {
    out[sbase + lane] = part[1] + part[3] + 2.f * b3v;
  }
}

extern "C" void kernel_launch(void* const* d_in, const int* in_sizes, int n_in,
                              void* d_out, int out_size, void* d_ws, size_t ws_size,
                              hipStream_t stream) {
  const int* uids = (const int*)d_in[0];
  const int* mids = (const int*)d_in[1];
  const float* EU = (const float*)d_in[2];
  const float* EM = (const float*)d_in[3];
  const float* W1 = (const float*)d_in[4];
  const float* B1 = (const float*)d_in[5];
  const float* W2 = (const float*)d_in[6];
  const float* B2 = (const float*)d_in[7];
  const float* W3 = (const float*)d_in[8];
  const float* B3 = (const float*)d_in[9];
  float* out = (float*)d_out;

  unsigned short* w1g = (unsigned short*)d_ws;          // 32 KB
  unsigned short* w2g = w1g + 16 * 1024;                // 64 KB

  hipLaunchKernelGGL(prep_weights, dim3(6), dim3(512), 0, stream,
                     W1, W2, w1g, w2g);

  const int B = in_sizes[0];  // 65536
  const int nblk = B / 128;   // 512 blocks x 128 samples, 2 blocks/CU
  hipLaunchKernelGGL(movielens_mlp, dim3(nblk), dim3(256), 0, stream,
                     uids, mids, EU, EM, w1g, B1, w2g, B2, W3, B3, out);
}

// Round 6
// 21.788 us; speedup vs baseline: 1.1837x; 1.1837x over previous
//
#include <hip/hip_runtime.h>

// out[i] = MLP(emb_user[uid[i]]) + MLP(emb_movie[mid[i]])
// MLP: relu(x@W1+b1) -> relu(@W2+b2) -> @W3+b3.  Single kernel, 32x32x16
// bf16 MFMA, fp32 acc.
//
// Layer-1 computes hT = W1'^T @ xT as [32ch]x[32 samples] tiles; W1 columns
// are stored sigma-permuted (sigma(p)=16(q>>1)+4(q&1)+8h+s for p=s+4h+8q) so
// that each lane's 16 accumulators, packed pairwise (cvt_pk(acc[2w],acc[2w+1])),
// are EXACTLY the two layer-2 B-fragments (ks=0 -> words 0..3, ks=1 -> 4..7).
// Register-only layer1->layer2 handoff: no h1 LDS, no shuffles. W2 unpermuted.
//
// LDS: w1f 32 frags (32KB) + w2f 64 frags (64KB) = 96KB, all fragment-order
// (1KB frag, read at base+lane*16, conflict-free).  512 thr = 8 waves; each
// wave owns 32 samples (user+movie = 2 B-input sets sharing weight frags).
// Grid 256 -> 1 block/CU, 2 waves/SIMD.  One barrier total.

typedef __attribute__((ext_vector_type(8))) short bf16x8;
typedef __attribute__((ext_vector_type(16))) float f32x16;

__device__ __forceinline__ unsigned int cvt_pk(float lo, float hi) {
  unsigned int r;
  asm("v_cvt_pk_bf16_f32 %0, %1, %2" : "=v"(r) : "v"(lo), "v"(hi));
  return r;  // bf16(lo) in [15:0], bf16(hi) in [31:16], RNE
}

__global__ __launch_bounds__(512, 2) void movielens_mlp(
    const int* __restrict__ uids, const int* __restrict__ mids,
    const float* __restrict__ EU, const float* __restrict__ EM,
    const float* __restrict__ W1, const float* __restrict__ B1,
    const float* __restrict__ W2, const float* __restrict__ B2,
    const float* __restrict__ W3, const float* __restrict__ B3,
    float* __restrict__ out) {
  __shared__ __align__(16) unsigned short w1f[32 * 512];  // 32 KB
  __shared__ __align__(16) unsigned short w2f[64 * 512];  // 64 KB

  const int tid = threadIdx.x;
  const int lane = tid & 63, wv = tid >> 6;
  const int m32 = lane & 31, H = lane >> 5;

  const int sbase = blockIdx.x * 256 + wv * 32;
  const int sid = sbase + m32;

  // ---- issue embedding gathers first (longest-latency chain) ----
  const float* rowU = EU + (size_t)uids[sid] * 64;
  const float* rowM = EM + (size_t)mids[sid] * 64;
  float4 xr[2][4][2];
#pragma unroll
  for (int kk = 0; kk < 4; ++kk) {
    xr[0][kk][0] = *(const float4*)(rowU + 16 * kk + 8 * H);
    xr[0][kk][1] = *(const float4*)(rowU + 16 * kk + 8 * H + 4);
    xr[1][kk][0] = *(const float4*)(rowM + 16 * kk + 8 * H);
    xr[1][kk][1] = *(const float4*)(rowM + 16 * kk + 8 * H + 4);
  }

  // ---- stage W1 (sigma-permuted) + W2 into A-frag order ----
  // unit = 4 rows x 4 cols; 1024 W1 units (i<2), 2048 W2 units (i>=2).
#pragma unroll
  for (int i = 0; i < 6; ++i) {
    const int u = tid + 512 * i;
    const int cq = u & 7, bb = (u >> 3) & 1, hh = (u >> 4) & 1;
    if (i < 2) {
      const int fi = u >> 5;  // ct*4 + kk
      const int ct = fi >> 2, kk = fi & 3;
      const float* src = W1 + (16 * kk + 8 * hh + 4 * bb) * 256 + 32 * ct + 4 * cq;
      const float4 r0 = *(const float4*)(src);
      const float4 r1 = *(const float4*)(src + 256);
      const float4 r2 = *(const float4*)(src + 512);
      const float4 r3 = *(const float4*)(src + 768);
      const float c0[4] = {r0.x, r0.y, r0.z, r0.w};
      const float c1[4] = {r1.x, r1.y, r1.z, r1.w};
      const float c2[4] = {r2.x, r2.y, r2.z, r2.w};
      const float c3[4] = {r3.x, r3.y, r3.z, r3.w};
      // sigma^-1(4cq+s) = p_base+s, p_base = 16(cq>>2) + 8(cq&1) + 4((cq>>1)&1)
      const int slot0 = 32 * hh + 16 * (cq >> 2) + 8 * (cq & 1) + 4 * ((cq >> 1) & 1);
#pragma unroll
      for (int s = 0; s < 4; ++s) {
        uint2 pk;
        pk.x = cvt_pk(c0[s], c1[s]);
        pk.y = cvt_pk(c2[s], c3[s]);
        *(uint2*)&w1f[fi * 512 + (slot0 + s) * 8 + 4 * bb] = pk;
      }
    } else {
      const int v = u - 1024;
      const int f2 = v >> 5;  // ks*4 + n2
      const int ks = f2 >> 2, n2 = f2 & 3;
      const float* src = W2 + (16 * ks + 8 * hh + 4 * bb) * 128 + 32 * n2 + 4 * cq;
      const float4 r0 = *(const float4*)(src);
      const float4 r1 = *(const float4*)(src + 128);
      const float4 r2 = *(const float4*)(src + 256);
      const float4 r3 = *(const float4*)(src + 384);
      const float c0[4] = {r0.x, r0.y, r0.z, r0.w};
      const float c1[4] = {r1.x, r1.y, r1.z, r1.w};
      const float c2[4] = {r2.x, r2.y, r2.z, r2.w};
      const float c3[4] = {r3.x, r3.y, r3.z, r3.w};
      const int slot0 = 32 * hh + 4 * cq;
#pragma unroll
      for (int s = 0; s < 4; ++s) {
        uint2 pk;
        pk.x = cvt_pk(c0[s], c1[s]);
        pk.y = cvt_pk(c2[s], c3[s]);
        *(uint2*)&w2f[f2 * 512 + (slot0 + s) * 8 + 4 * bb] = pk;
      }
    }
  }

  // ---- convert gathers to layer-1 B-frags: lane holds x[sample m32][8H+j] ----
  bf16x8 xf[2][4];
#pragma unroll
  for (int t = 0; t < 2; ++t)
#pragma unroll
    for (int kk = 0; kk < 4; ++kk) {
      const float4 a = xr[t][kk][0], b = xr[t][kk][1];
      uint4 w;
      w.x = cvt_pk(a.x, a.y);
      w.y = cvt_pk(a.z, a.w);
      w.z = cvt_pk(b.x, b.y);
      w.w = cvt_pk(b.z, b.w);
      xf[t][kk] = __builtin_bit_cast(bf16x8, w);
    }
  __syncthreads();

  // ---- layer-2 accumulators, bias-initialized ----
  // acc2[t][n2] holds D2: col=sample m32, row p2(r)= (r&3)+8(r>>2)+4H.
  f32x16 acc2[2][4];
#pragma unroll
  for (int n2 = 0; n2 < 4; ++n2)
#pragma unroll
    for (int rq = 0; rq < 4; ++rq) {
      const float4 bq = *(const float4*)(B2 + 32 * n2 + 8 * rq + 4 * H);
      const float bv[4] = {bq.x, bq.y, bq.z, bq.w};
#pragma unroll
      for (int s = 0; s < 4; ++s) {
        acc2[0][n2][4 * rq + s] = bv[s];
        acc2[1][n2][4 * rq + s] = bv[s];
      }
    }

  // ---- main loop: 8 chunks of 32 layer-1 channels ----
  bf16x8 a1[4];
#pragma unroll
  for (int kk = 0; kk < 4; ++kk)
    a1[kk] = *(const bf16x8*)&w1f[kk * 512 + lane * 8];

#pragma unroll 2
  for (int ct = 0; ct < 8; ++ct) {
    // layer-1, t=0 (user): bias init + 4 MFMA
    f32x16 acc1a;
    {
      const float4 q0 = *(const float4*)(B1 + 32 * ct + 8 * H);
      const float4 q1 = *(const float4*)(B1 + 32 * ct + 8 * H + 4);
      const float4 q2 = *(const float4*)(B1 + 32 * ct + 8 * H + 16);
      const float4 q3 = *(const float4*)(B1 + 32 * ct + 8 * H + 20);
      acc1a[0]=q0.x; acc1a[1]=q0.y; acc1a[2]=q0.z; acc1a[3]=q0.w;
      acc1a[4]=q1.x; acc1a[5]=q1.y; acc1a[6]=q1.z; acc1a[7]=q1.w;
      acc1a[8]=q2.x; acc1a[9]=q2.y; acc1a[10]=q2.z; acc1a[11]=q2.w;
      acc1a[12]=q3.x; acc1a[13]=q3.y; acc1a[14]=q3.z; acc1a[15]=q3.w;
    }
#pragma unroll
    for (int kk = 0; kk < 4; ++kk)
      acc1a = __builtin_amdgcn_mfma_f32_32x32x16_bf16(a1[kk], xf[0][kk], acc1a, 0, 0, 0);

    // issue W2 frag reads for this chunk (latency hides under packs/MFMAs)
    bf16x8 w2v[8];
#pragma unroll
    for (int q = 0; q < 8; ++q)
      w2v[q] = *(const bf16x8*)&w2f[(8 * ct + q) * 512 + lane * 8];

    // pack t=0: acc pairs ARE the layer-2 B-frag words (sigma trick)
    uint4 lo0, hi0;
    lo0.x = cvt_pk(fmaxf(acc1a[0], 0.f), fmaxf(acc1a[1], 0.f));
    lo0.y = cvt_pk(fmaxf(acc1a[2], 0.f), fmaxf(acc1a[3], 0.f));
    lo0.z = cvt_pk(fmaxf(acc1a[4], 0.f), fmaxf(acc1a[5], 0.f));
    lo0.w = cvt_pk(fmaxf(acc1a[6], 0.f), fmaxf(acc1a[7], 0.f));
    hi0.x = cvt_pk(fmaxf(acc1a[8], 0.f), fmaxf(acc1a[9], 0.f));
    hi0.y = cvt_pk(fmaxf(acc1a[10], 0.f), fmaxf(acc1a[11], 0.f));
    hi0.z = cvt_pk(fmaxf(acc1a[12], 0.f), fmaxf(acc1a[13], 0.f));
    hi0.w = cvt_pk(fmaxf(acc1a[14], 0.f), fmaxf(acc1a[15], 0.f));

    // layer-1, t=1 (movie)
    f32x16 acc1b;
    {
      const float4 q0 = *(const float4*)(B1 + 32 * ct + 8 * H);
      const float4 q1 = *(const float4*)(B1 + 32 * ct + 8 * H + 4);
      const float4 q2 = *(const float4*)(B1 + 32 * ct + 8 * H + 16);
      const float4 q3 = *(const float4*)(B1 + 32 * ct + 8 * H + 20);
      acc1b[0]=q0.x; acc1b[1]=q0.y; acc1b[2]=q0.z; acc1b[3]=q0.w;
      acc1b[4]=q1.x; acc1b[5]=q1.y; acc1b[6]=q1.z; acc1b[7]=q1.w;
      acc1b[8]=q2.x; acc1b[9]=q2.y; acc1b[10]=q2.z; acc1b[11]=q2.w;
      acc1b[12]=q3.x; acc1b[13]=q3.y; acc1b[14]=q3.z; acc1b[15]=q3.w;
    }
#pragma unroll
    for (int kk = 0; kk < 4; ++kk)
      acc1b = __builtin_amdgcn_mfma_f32_32x32x16_bf16(a1[kk], xf[1][kk], acc1b, 0, 0, 0);

    // prefetch next chunk's W1 frags (hides under layer-2 MFMAs)
    if (ct < 7) {
#pragma unroll
      for (int kk = 0; kk < 4; ++kk)
        a1[kk] = *(const bf16x8*)&w1f[((ct + 1) * 4 + kk) * 512 + lane * 8];
    }

    // layer-2, t=0
#pragma unroll
    for (int n2 = 0; n2 < 4; ++n2) {
      acc2[0][n2] = __builtin_amdgcn_mfma_f32_32x32x16_bf16(
          w2v[n2], __builtin_bit_cast(bf16x8, lo0), acc2[0][n2], 0, 0, 0);
      acc2[0][n2] = __builtin_amdgcn_mfma_f32_32x32x16_bf16(
          w2v[4 + n2], __builtin_bit_cast(bf16x8, hi0), acc2[0][n2], 0, 0, 0);
    }

    // pack t=1
    uint4 lo1, hi1;
    lo1.x = cvt_pk(fmaxf(acc1b[0], 0.f), fmaxf(acc1b[1], 0.f));
    lo1.y = cvt_pk(fmaxf(acc1b[2], 0.f), fmaxf(acc1b[3], 0.f));
    lo1.z = cvt_pk(fmaxf(acc1b[4], 0.f), fmaxf(acc1b[5], 0.f));
    lo1.w = cvt_pk(fmaxf(acc1b[6], 0.f), fmaxf(acc1b[7], 0.f));
    hi1.x = cvt_pk(fmaxf(acc1b[8], 0.f), fmaxf(acc1b[9], 0.f));
    hi1.y = cvt_pk(fmaxf(acc1b[10], 0.f), fmaxf(acc1b[11], 0.f));
    hi1.z = cvt_pk(fmaxf(acc1b[12], 0.f), fmaxf(acc1b[13], 0.f));
    hi1.w = cvt_pk(fmaxf(acc1b[14], 0.f), fmaxf(acc1b[15], 0.f));

    // layer-2, t=1
#pragma unroll
    for (int n2 = 0; n2 < 4; ++n2) {
      acc2[1][n2] = __builtin_amdgcn_mfma_f32_32x32x16_bf16(
          w2v[n2], __builtin_bit_cast(bf16x8, lo1), acc2[1][n2], 0, 0, 0);
      acc2[1][n2] = __builtin_amdgcn_mfma_f32_32x32x16_bf16(
          w2v[4 + n2], __builtin_bit_cast(bf16x8, hi1), acc2[1][n2], 0, 0, 0);
    }
  }

  // ---- layer 3: relu(h2) . W3; rows split across lane halves ----
  float part = 0.f;
#pragma unroll
  for (int n2 = 0; n2 < 4; ++n2) {
#pragma unroll
    for (int rq = 0; rq < 4; ++rq) {
      const float4 wq = *(const float4*)(W3 + 32 * n2 + 8 * rq + 4 * H);
      const float wv4[4] = {wq.x, wq.y, wq.z, wq.w};
#pragma unroll
      for (int s = 0; s < 4; ++s) {
        part += fmaxf(acc2[0][n2][4 * rq + s], 0.f) * wv4[s];
        part += fmaxf(acc2[1][n2][4 * rq + s], 0.f) * wv4[s];
      }
    }
  }
  part += __shfl_xor(part, 32, 64);  // combine row-halves (same sample)
  if (lane < 32) out[sbase + lane] = part + 2.f * B3[0];
}

extern "C" void kernel_launch(void* const* d_in, const int* in_sizes, int n_in,
                              void* d_out, int out_size, void* d_ws, size_t ws_size,
                              hipStream_t stream) {
  const int* uids = (const int*)d_in[0];
  const int* mids = (const int*)d_in[1];
  const float* EU = (const float*)d_in[2];
  const float* EM = (const float*)d_in[3];
  const float* W1 = (const float*)d_in[4];
  const float* B1 = (const float*)d_in[5];
  const float* W2 = (const float*)d_in[6];
  const float* B2 = (const float*)d_in[7];
  const float* W3 = (const float*)d_in[8];
  const float* B3 = (const float*)d_in[9];
  float* out = (float*)d_out;

  const int B = in_sizes[0];  // 65536
  const int nblk = B / 256;   // 256 blocks x 256 samples
  hipLaunchKernelGGL(movielens_mlp, dim3(nblk), dim3(512), 0, stream,
                     uids, mids, EU, EM, W1, B1, W2, B2, W3, B3, out);
}